// Round 8
// baseline (138.734 us; speedup 1.0000x reference)
//
#include <hip/hip_runtime.h>

#define DDIM 256
#define HDIM 128
#define KLEN 1024
// 2*log2(e): exp2(SCL*x) == e^{2x}
#define SCL 2.8853900817779268f

typedef float f8 __attribute__((ext_vector_type(8)));

// ============ Projection -> Eq/Ek = exp2(SCL * in@W) ============
// v7 = v2 + explicit W prefetch. v2's structure is the only one that beats
// the LDS instruction pipe (FMA:LDS = 32:1 >= 24 needed; ds_read_b128 ~12
// cy/instr/CU vs FMA 2 instr/cy). v2's residual stall was the W fetch:
// SGPR=32 showed no hoisting -> serial fetch->wait->FMA. Now each W row is
// ONE 32B f8 load (uniform addr -> s_load_dwordx8 / dwordx4 pair),
// double-buffered one d4-step ahead so W latency hides under the 32 FMA.
// Block = 64 rows x 32 h = 4 waves; wave owns 8 h, lane owns 1 row.
// A-tile (64x64) in LDS, XOR-swizzled, b128 reads 2-way = free.
// Grid 1088 (4.25/CU): 1024 key blocks (XCD-swizzled) + 64 query.
// Output layouts: Eq row-major [row][128], Ek [b][h][k], exp2 applied.
__global__ __launch_bounds__(256) void proj_kernel(
    const float* __restrict__ queries, const float* __restrict__ keys,
    const float* __restrict__ W_q, const float* __restrict__ W_k,
    float* __restrict__ Eq, float* __restrict__ Ek)
{
    __shared__ union {
        float a[64 * 64];    // 16 KB A-tile (swizzled)
        float t[32][68];     // epilogue transpose staging (keys), pad 64->68
    } sm;

    const int tid  = threadIdx.x;
    const int lane = tid & 63;
    const int wav  = tid >> 6;

    int blk = blockIdx.x;
    bool iskey; int b = 0, kc0 = 0, hb, row0;
    const float* in; const float* W;
    if (blk < 1024) {
        iskey = true;
        int xcd = blk & 7, s = blk >> 3;
        b = ((s >> 6) << 3) | xcd;
        int r6 = s & 63;
        kc0 = (r6 >> 2) << 6;     // 16 k-chunks of 64
        hb  = (r6 & 3) << 5;      // 4 h-chunks of 32
        row0 = b * KLEN + kc0;
        in = keys; W = W_k;
    } else {
        iskey = false;
        int qrb = blk - 1024;     // 0..63
        row0 = (qrb >> 2) << 6;
        hb   = (qrb & 3) << 5;
        in = queries; W = W_q;
    }

    // wave-uniform h-base -> W accesses are uniform 32B rows
    const int hg8 = __builtin_amdgcn_readfirstlane(wav << 3);
    const float* Wu = W + hb + hg8;

    // staging: 4 x 16B granules per thread per 64-d step, coalesced reads
    const int srow = tid >> 4;        // 0..15 (+16*i covers 64 rows)
    const int sgd  = tid & 15;        // 16B granule within 64-d row slice
    const float* gsrc = in + (size_t)(row0 + srow) * DDIM + (sgd << 2);

    float4 pf0 = *(const float4*)(gsrc);
    float4 pf1 = *(const float4*)(gsrc + 16 * DDIM);
    float4 pf2 = *(const float4*)(gsrc + 32 * DDIM);
    float4 pf3 = *(const float4*)(gsrc + 48 * DDIM);

    float acc[8];
    #pragma unroll
    for (int c = 0; c < 8; c++) acc[c] = 0.f;

    // XOR-swizzled LDS write offsets (float index): granule ^= (row & 7)
    const int w0 = (srow)      * 64 + ((sgd ^ ((srow)      & 7)) << 2);
    const int w1 = (srow + 16) * 64 + ((sgd ^ ((srow + 16) & 7)) << 2);
    const int w2 = (srow + 32) * 64 + ((sgd ^ ((srow + 32) & 7)) << 2);
    const int w3 = (srow + 48) * 64 + ((sgd ^ ((srow + 48) & 7)) << 2);

    // W double-buffer: rows d..d+3 as f8 (32B) each, prefetched 1 step ahead
    f8 wa[4];
    #pragma unroll
    for (int i = 0; i < 4; i++)
        wa[i] = *(const f8*)(Wu + (size_t)i * HDIM);

    for (int dt0 = 0; dt0 < DDIM; dt0 += 64) {
        *(float4*)(sm.a + w0) = pf0;
        *(float4*)(sm.a + w1) = pf1;
        *(float4*)(sm.a + w2) = pf2;
        *(float4*)(sm.a + w3) = pf3;
        __syncthreads();
        if (dt0 < DDIM - 64) {        // prefetch next d-tile under compute
            const float* g2 = gsrc + dt0 + 64;
            pf0 = *(const float4*)(g2);
            pf1 = *(const float4*)(g2 + 16 * DDIM);
            pf2 = *(const float4*)(g2 + 32 * DDIM);
            pf3 = *(const float4*)(g2 + 48 * DDIM);
        }
        const float* arow = sm.a + lane * 64;
        const int lx = lane & 7;
        #pragma unroll
        for (int d4 = 0; d4 < 64; d4 += 4) {
            // prefetch next step's 4 W rows (stream is d-linear, tile-independent)
            const int dg = dt0 + d4;
            const int dn = (dg + 4 <= DDIM - 4) ? (dg + 4) : dg;  // clamp at end
            f8 wn[4];
            #pragma unroll
            for (int i = 0; i < 4; i++)
                wn[i] = *(const f8*)(Wu + (size_t)(dn + i) * HDIM);

            float4 a = *(const float4*)(arow + ((((d4 >> 2)) ^ lx) << 2));
            #pragma unroll
            for (int c = 0; c < 8; c++) acc[c] = fmaf(a.x, wa[0][c], acc[c]);
            #pragma unroll
            for (int c = 0; c < 8; c++) acc[c] = fmaf(a.y, wa[1][c], acc[c]);
            #pragma unroll
            for (int c = 0; c < 8; c++) acc[c] = fmaf(a.z, wa[2][c], acc[c]);
            #pragma unroll
            for (int c = 0; c < 8; c++) acc[c] = fmaf(a.w, wa[3][c], acc[c]);
            #pragma unroll
            for (int i = 0; i < 4; i++) wa[i] = wn[i];
        }
        __syncthreads();   // compute done before next tile overwrites LDS
    }

    float e[8];
    #pragma unroll
    for (int c = 0; c < 8; c++) e[c] = __builtin_amdgcn_exp2f(SCL * acc[c]);

    if (!iskey) {
        float* dst = Eq + (size_t)(row0 + lane) * HDIM + hb + hg8;
        *(float4*)(dst)     = make_float4(e[0], e[1], e[2], e[3]);
        *(float4*)(dst + 4) = make_float4(e[4], e[5], e[6], e[7]);
    } else {
        // transpose 64k x 32h -> t[h][k], then coalesced 256B-row stores
        #pragma unroll
        for (int c = 0; c < 8; c++) sm.t[(wav << 3) + c][lane] = e[c];
        __syncthreads();
        float* dstb = Ek + (size_t)b * HDIM * KLEN + (size_t)hb * KLEN + kc0;
        #pragma unroll
        for (int i = 0; i < 2; i++) {
            int g = tid + (i << 8);
            int h = g >> 4, k4 = (g & 15) << 2;
            float4 o = *(const float4*)(&sm.t[h][k4]);
            *(float4*)(dstb + (size_t)h * KLEN + k4) = o;
        }
    }
}

// ============ FUSED scores + E@V (normalization-free) ============
// Grid 1024 = (16 b x 8 qt x 8 kq), XCD-matched to proj's Ek[b] placement;
// 256 thr (4 waves) -> 4 blocks/CU, 16 waves/CU.
// Phase 1 (score, v1's proven direct-L2 regime): thread = 2q x 2k over all
// 128 h; Ek streamed from global (coalesced 512B/wave float2 loads, 8-deep
// reg dual-buffer); (eq0,eq1,w2) as ONE broadcast float4/h from LDS. E tile
// (8q x 128k, masked-zero exp) -> 4 KB LDS. One barrier.
// Phase 2 (av v4's proven loop): wave owns exclusive 32 k; per k one
// fully-coalesced 1KB/wave V float4 row + 2 broadcast b128 E reads ->
// 32 fma + 8 T-adds (wave-uniform). Slab reduce -> part[kq] + Tp[kq].
// Softmax algebra: Sum(w) constant and max-shift cancel in (E@V)/T;
// |s|<~25 -> exp fp32-safe. Unconditional stores -> poison-safe.
__global__ __launch_bounds__(256) void score_av_kernel(
    const float* __restrict__ Eq, const float* __restrict__ Ek,
    const float* __restrict__ w_v, const int* __restrict__ valid_lens,
    const float* __restrict__ values,
    float* __restrict__ part, float* __restrict__ Tp)
{
    __shared__ union {
        struct {
            float4 eqw[4][HDIM];   // (eq_q0, eq_q1, -2w, 0) per wave  8 KB
            float  el[128][8];     // E tile [k][q]                    4 KB
        } p;
        float4 slab[4][8][64];     // 32 KB cross-wave reduce
    } sm;
    __shared__ float tslab[4][8];

    const int tid = threadIdx.x;
    const int lane = tid & 63, wav = tid >> 6;
    int blk = blockIdx.x;
    int xcd = blk & 7, s = blk >> 3;          // 0..127
    int b = ((s >> 6) << 3) | xcd;
    int r = s & 63;
    int qt = r >> 3, kq = r & 7;
    int bq0 = b * 64 + qt * 8;
    int k0g = kq << 7;                        // global k base of 128-slice
    int vlen = valid_lens[b];

    // ---- prologue: pack eqw (coalesced one-time global reads) ----
    #pragma unroll
    for (int i = 0; i < 2; i++) {
        int slot = tid + (i << 8);            // 512 slots = 4 waves x 128 h
        int w = slot >> 7, h = slot & 127;
        sm.p.eqw[w][h] = make_float4(
            Eq[(size_t)(bq0 + 2 * w) * HDIM + h],
            Eq[(size_t)(bq0 + 2 * w + 1) * HDIM + h],
            -2.0f * w_v[h], 0.f);
    }
    __syncthreads();

    // ---- phase 1: scores for (2q x 2k), h-streamed, 8-deep reg dbuf ----
    const int kl = lane << 1;                 // lane's 2 k within slice
    const float* ekp = Ek + (size_t)b * HDIM * KLEN + k0g + kl;
    float2 buf[8];
    #pragma unroll
    for (int j = 0; j < 8; j++)
        buf[j] = *(const float2*)(ekp + (size_t)j * KLEN);

    float2 acc0 = make_float2(0.f, 0.f), acc1 = make_float2(0.f, 0.f);
    for (int h0 = 0; h0 < HDIM; h0 += 8) {
        float2 nxt[8];
        if (h0 < HDIM - 8) {
            #pragma unroll
            for (int j = 0; j < 8; j++)
                nxt[j] = *(const float2*)(ekp + (size_t)(h0 + 8 + j) * KLEN);
        }
        #pragma unroll
        for (int j = 0; j < 8; j++) {
            float4 e = sm.p.eqw[wav][h0 + j];
            float2 ek = buf[j];
            acc0.x = fmaf(e.z, __builtin_amdgcn_rcpf(fmaf(e.x, ek.x, 1.f)), acc0.x);
            acc0.y = fmaf(e.z, __builtin_amdgcn_rcpf(fmaf(e.x, ek.y, 1.f)), acc0.y);
            acc1.x = fmaf(e.z, __builtin_amdgcn_rcpf(fmaf(e.y, ek.x, 1.f)), acc1.x);
            acc1.y = fmaf(e.z, __builtin_amdgcn_rcpf(fmaf(e.y, ek.y, 1.f)), acc1.y);
        }
        #pragma unroll
        for (int j = 0; j < 8; j++) buf[j] = nxt[j];
    }

    {   // masked exp -> E tile in LDS (el[k][q]); one-time write
        int kg = k0g + kl;
        float e00 = (kg     < vlen) ? __expf(acc0.x) : 0.f;   // q0, k
        float e01 = (kg + 1 < vlen) ? __expf(acc0.y) : 0.f;   // q0, k+1
        float e10 = (kg     < vlen) ? __expf(acc1.x) : 0.f;   // q1, k
        float e11 = (kg + 1 < vlen) ? __expf(acc1.y) : 0.f;   // q1, k+1
        *(float2*)(&sm.p.el[kl][2 * wav])     = make_float2(e00, e10);
        *(float2*)(&sm.p.el[kl + 1][2 * wav]) = make_float2(e01, e11);
    }
    __syncthreads();

    // ---- phase 2: E @ V, wave-exclusive 32-k slice ----
    int kw = wav << 5;                        // wave's k-local base
    int kg0 = k0g + kw;
    int cnt = vlen - kg0; cnt = cnt < 0 ? 0 : (cnt > 32 ? 32 : cnt);
    int cnt4 = (cnt + 3) & ~3;                // el == 0 beyond vlen -> safe
    const float* vb = values + ((size_t)b * KLEN + kg0) * DDIM + (lane << 2);

    float4 acc[8];
    float acct[8];
    #pragma unroll
    for (int q = 0; q < 8; q++) { acc[q] = make_float4(0.f, 0.f, 0.f, 0.f); acct[q] = 0.f; }

    for (int k = 0; k < cnt4; k += 4) {
        #pragma unroll
        for (int j = 0; j < 4; j++) {
            float4 v  = *(const float4*)(vb + (size_t)(k + j) * DDIM);
            float4 p0 = *(const float4*)(&sm.p.el[kw + k + j][0]);
            float4 p1 = *(const float4*)(&sm.p.el[kw + k + j][4]);
            float pq[8] = {p0.x, p0.y, p0.z, p0.w, p1.x, p1.y, p1.z, p1.w};
            #pragma unroll
            for (int q = 0; q < 8; q++) {
                acc[q].x = fmaf(pq[q], v.x, acc[q].x);
                acc[q].y = fmaf(pq[q], v.y, acc[q].y);
                acc[q].z = fmaf(pq[q], v.z, acc[q].z);
                acc[q].w = fmaf(pq[q], v.w, acc[q].w);
                acct[q] += pq[q];
            }
        }
    }

    __syncthreads();               // el reads done; overwrite with slab
    #pragma unroll
    for (int q = 0; q < 8; q++) sm.slab[wav][q][lane] = acc[q];
    if (lane == 0) {
        #pragma unroll
        for (int q = 0; q < 8; q++) tslab[wav][q] = acct[q];
    }
    __syncthreads();
    #pragma unroll
    for (int e = 0; e < 2; e++) {
        int slot = (tid << 1) | e;         // 512 output f4 slots
        int q = slot >> 6, d4 = slot & 63;
        float4 a = sm.slab[0][q][d4];
        #pragma unroll
        for (int g = 1; g < 4; g++) {
            float4 t = sm.slab[g][q][d4];
            a.x += t.x; a.y += t.y; a.z += t.z; a.w += t.w;
        }
        *(float4*)(part + ((size_t)kq * 1024 + bq0 + q) * DDIM + (d4 << 2)) = a;
    }
    if (tid < 8) {
        float t = tslab[0][tid] + tslab[1][tid] + tslab[2][tid] + tslab[3][tid];
        Tp[(size_t)kq * 1024 + bq0 + tid] = t;
    }
}

// ============ sum 8 kq-partials, normalize by T ============
__global__ __launch_bounds__(256) void combine_kernel(
    const float* __restrict__ part, const float* __restrict__ Tp,
    float* __restrict__ out)
{
    int i = blockIdx.x * 256 + threadIdx.x;        // 65536 float4 slots
    int row = i >> 6;                              // 0..1023 (b*64+q)
    const float4* p4 = (const float4*)part;
    float t = 0.f;
    #pragma unroll
    for (int j = 0; j < 8; j++) t += Tp[(size_t)j * 1024 + row];
    float inv = 1.0f / t;
    float4 a = p4[i];
    #pragma unroll
    for (int j = 1; j < 8; j++) {
        float4 v = p4[(size_t)j * 65536 + i];
        a.x += v.x; a.y += v.y; a.z += v.z; a.w += v.w;
    }
    a.x *= inv; a.y *= inv; a.z *= inv; a.w *= inv;
    ((float4*)out)[i] = a;
}

extern "C" void kernel_launch(void* const* d_in, const int* in_sizes, int n_in,
                              void* d_out, int out_size, void* d_ws, size_t ws_size,
                              hipStream_t stream) {
    const float* queries    = (const float*)d_in[0]; // [16,64,256]
    const float* keys       = (const float*)d_in[1]; // [16,1024,256]
    const float* values     = (const float*)d_in[2]; // [16,1024,256]
    const int*   valid_lens = (const int*)d_in[3];   // [16]
    const float* W_q        = (const float*)d_in[4]; // [256,128]
    const float* W_k        = (const float*)d_in[5]; // [256,128]
    const float* w_v        = (const float*)d_in[6]; // [128]

    float* Eq   = (float*)d_ws;            // 1024*128      = 512 KB
    float* Ek   = Eq + 131072;             // 16*128*1024   = 8 MB
    float* part = Ek + 2097152;            // 8*1024*256    = 8 MB (no alias: Ek live)
    float* Tp   = part + 2097152;          // 8*1024 floats = 32 KB

    proj_kernel<<<1088, 256, 0, stream>>>(queries, keys, W_q, W_k, Eq, Ek);
    score_av_kernel<<<1024, 256, 0, stream>>>(Eq, Ek, w_v, valid_lens, values, part, Tp);
    combine_kernel<<<256, 256, 0, stream>>>(part, Tp, (float*)d_out);
}

// Round 9
// 137.683 us; speedup vs baseline: 1.0076x; 1.0076x over previous
//
#include <hip/hip_runtime.h>

#define DDIM 256
#define HDIM 128
#define KLEN 1024
// 2*log2(e): exp2(SCL*x) == e^{2x}
#define SCL 2.8853900817779268f

// ============ Projection -> Eq/Ek = exp2(SCL * in@W) ============
// v2 (proven 33us): wave-uniform W (scalar s_load path) x per-lane rows.
// Block = 64 rows x 32 h = 4 waves; each wave owns 8 h, each lane owns 1 row.
// A-tile (64 rows x 64 d) in LDS, XOR-swizzled on 16B granules so each
// lane's ds_read_b128 of its own row is <=2-way (free). W operands are
// wave-uniform -> scalar loads, costing no VALU/VMEM/LDS bandwidth.
// Grid 1088 (4.25 blocks/CU): 1024 key blocks (XCD-swizzled) + 64 query.
// Output layouts: Eq row-major [row][128], Ek [b][h][k], exp2 applied.
__global__ __launch_bounds__(256) void proj_kernel(
    const float* __restrict__ queries, const float* __restrict__ keys,
    const float* __restrict__ W_q, const float* __restrict__ W_k,
    float* __restrict__ Eq, float* __restrict__ Ek)
{
    __shared__ union {
        float a[64 * 64];    // 16 KB A-tile (swizzled)
        float t[32][68];     // epilogue transpose staging (keys), pad 64->68
    } sm;

    const int tid  = threadIdx.x;
    const int lane = tid & 63;
    const int wav  = tid >> 6;

    int blk = blockIdx.x;
    bool iskey; int b = 0, kc0 = 0, hb, row0;
    const float* in; const float* W;
    if (blk < 1024) {
        iskey = true;
        int xcd = blk & 7, s = blk >> 3;
        b = ((s >> 6) << 3) | xcd;
        int r6 = s & 63;
        kc0 = (r6 >> 2) << 6;     // 16 k-chunks of 64
        hb  = (r6 & 3) << 5;      // 4 h-chunks of 32
        row0 = b * KLEN + kc0;
        in = keys; W = W_k;
    } else {
        iskey = false;
        int qrb = blk - 1024;     // 0..63
        row0 = (qrb >> 2) << 6;
        hb   = (qrb & 3) << 5;
        in = queries; W = W_q;
    }

    // wave-uniform h-base -> W accesses become scalar loads
    const int hg8 = __builtin_amdgcn_readfirstlane(wav << 3);
    const float* Wu = W + hb + hg8;

    // staging: 4 x 16B granules per thread per 64-d step, coalesced reads
    const int srow = tid >> 4;        // 0..15 (+16*i covers 64 rows)
    const int sgd  = tid & 15;        // 16B granule within 64-d row slice
    const float* gsrc = in + (size_t)(row0 + srow) * DDIM + (sgd << 2);

    float4 pf0 = *(const float4*)(gsrc);
    float4 pf1 = *(const float4*)(gsrc + 16 * DDIM);
    float4 pf2 = *(const float4*)(gsrc + 32 * DDIM);
    float4 pf3 = *(const float4*)(gsrc + 48 * DDIM);

    float acc[8];
    #pragma unroll
    for (int c = 0; c < 8; c++) acc[c] = 0.f;

    // XOR-swizzled LDS write offsets (float index): granule ^= (row & 7)
    const int w0 = (srow)      * 64 + ((sgd ^ ((srow)      & 7)) << 2);
    const int w1 = (srow + 16) * 64 + ((sgd ^ ((srow + 16) & 7)) << 2);
    const int w2 = (srow + 32) * 64 + ((sgd ^ ((srow + 32) & 7)) << 2);
    const int w3 = (srow + 48) * 64 + ((sgd ^ ((srow + 48) & 7)) << 2);

    for (int dt0 = 0; dt0 < DDIM; dt0 += 64) {
        *(float4*)(sm.a + w0) = pf0;
        *(float4*)(sm.a + w1) = pf1;
        *(float4*)(sm.a + w2) = pf2;
        *(float4*)(sm.a + w3) = pf3;
        __syncthreads();
        if (dt0 < DDIM - 64) {        // prefetch next d-tile under compute
            const float* g2 = gsrc + dt0 + 64;
            pf0 = *(const float4*)(g2);
            pf1 = *(const float4*)(g2 + 16 * DDIM);
            pf2 = *(const float4*)(g2 + 32 * DDIM);
            pf3 = *(const float4*)(g2 + 48 * DDIM);
        }
        const float* arow = sm.a + lane * 64;
        const int lx = lane & 7;
        #pragma unroll
        for (int d4 = 0; d4 < 64; d4 += 4) {
            float4 a = *(const float4*)(arow + ((((d4 >> 2)) ^ lx) << 2));
            const float* wr = Wu + (size_t)(dt0 + d4) * HDIM;
            #pragma unroll
            for (int c = 0; c < 8; c++) acc[c] = fmaf(a.x, wr[c],            acc[c]);
            #pragma unroll
            for (int c = 0; c < 8; c++) acc[c] = fmaf(a.y, wr[HDIM + c],     acc[c]);
            #pragma unroll
            for (int c = 0; c < 8; c++) acc[c] = fmaf(a.z, wr[2 * HDIM + c], acc[c]);
            #pragma unroll
            for (int c = 0; c < 8; c++) acc[c] = fmaf(a.w, wr[3 * HDIM + c], acc[c]);
        }
        __syncthreads();   // compute done before next tile overwrites LDS
    }

    float e[8];
    #pragma unroll
    for (int c = 0; c < 8; c++) e[c] = __builtin_amdgcn_exp2f(SCL * acc[c]);

    if (!iskey) {
        float* dst = Eq + (size_t)(row0 + lane) * HDIM + hb + hg8;
        *(float4*)(dst)     = make_float4(e[0], e[1], e[2], e[3]);
        *(float4*)(dst + 4) = make_float4(e[4], e[5], e[6], e[7]);
    } else {
        // transpose 64k x 32h -> t[h][k], then coalesced 256B-row stores
        #pragma unroll
        for (int c = 0; c < 8; c++) sm.t[(wav << 3) + c][lane] = e[c];
        __syncthreads();
        float* dstb = Ek + (size_t)b * HDIM * KLEN + (size_t)hb * KLEN + kc0;
        #pragma unroll
        for (int i = 0; i < 2; i++) {
            int g = tid + (i << 8);
            int h = g >> 4, k4 = (g & 15) << 2;
            float4 o = *(const float4*)(&sm.t[h][k4]);
            *(float4*)(dstb + (size_t)h * KLEN + k4) = o;
        }
    }
}

// ============ FUSED scores + E@V (normalization-free) ============
// v2: + vlen block-skip. Grid 1024 = (16 b x 8 qt x 8 kq), XCD-matched to
// proj's Ek[b] placement; 256 thr (4 waves).
// SKIP: if k0g >= vlen the whole 128-k slice is masked -> E tile == 0 ->
// contribution is exactly zero: write zero part/Tp and exit (block-uniform
// branch, barrier-safe; ~44% of blocks on avg for vlen~U(1,K)). Every row
// keeps kq=0 (vlen>=1) so T>0 in combine.
// Phase 1 (score): thread = 2q x 2k over all 128 h; Ek streamed from L2
// (coalesced 512B/wave float2 loads, 8-deep reg dbuf); (eq0,eq1,w2) as one
// broadcast float4/h from LDS. E tile (8q x 128k, masked exp) -> 4 KB LDS.
// Phase 2 (E@V): wave owns exclusive 32 k; per k one coalesced 1KB/wave V
// row + 2 broadcast b128 E reads -> 32 fma + 8 T-adds. Slab reduce.
// Softmax algebra: Sum(w) const and max-shift cancel in (E@V)/T; |s|<~25
// -> exp fp32-safe. Unconditional stores -> poison-safe.
__global__ __launch_bounds__(256) void score_av_kernel(
    const float* __restrict__ Eq, const float* __restrict__ Ek,
    const float* __restrict__ w_v, const int* __restrict__ valid_lens,
    const float* __restrict__ values,
    float* __restrict__ part, float* __restrict__ Tp)
{
    __shared__ union {
        struct {
            float4 eqw[4][HDIM];   // (eq_q0, eq_q1, -2w, 0) per wave  8 KB
            float  el[128][8];     // E tile [k][q]                    4 KB
        } p;
        float4 slab[4][8][64];     // 32 KB cross-wave reduce
    } sm;
    __shared__ float tslab[4][8];

    const int tid = threadIdx.x;
    const int lane = tid & 63, wav = tid >> 6;
    int blk = blockIdx.x;
    int xcd = blk & 7, s = blk >> 3;          // 0..127
    int b = ((s >> 6) << 3) | xcd;
    int r = s & 63;
    int qt = r >> 3, kq = r & 7;
    int bq0 = b * 64 + qt * 8;
    int k0g = kq << 7;                        // global k base of 128-slice
    int vlen = valid_lens[b];

    if (k0g >= vlen) {                        // fully-masked slice: zeros
        float4 z = make_float4(0.f, 0.f, 0.f, 0.f);
        #pragma unroll
        for (int e = 0; e < 2; e++) {
            int slot = (tid << 1) | e;
            int q = slot >> 6, d4 = slot & 63;
            *(float4*)(part + ((size_t)kq * 1024 + bq0 + q) * DDIM + (d4 << 2)) = z;
        }
        if (tid < 8) Tp[(size_t)kq * 1024 + bq0 + tid] = 0.f;
        return;
    }

    // ---- prologue: pack eqw (coalesced one-time global reads) ----
    #pragma unroll
    for (int i = 0; i < 2; i++) {
        int slot = tid + (i << 8);            // 512 slots = 4 waves x 128 h
        int w = slot >> 7, h = slot & 127;
        sm.p.eqw[w][h] = make_float4(
            Eq[(size_t)(bq0 + 2 * w) * HDIM + h],
            Eq[(size_t)(bq0 + 2 * w + 1) * HDIM + h],
            -2.0f * w_v[h], 0.f);
    }
    __syncthreads();

    // ---- phase 1: scores for (2q x 2k), h-streamed, 8-deep reg dbuf ----
    const int kl = lane << 1;                 // lane's 2 k within slice
    const float* ekp = Ek + (size_t)b * HDIM * KLEN + k0g + kl;
    float2 buf[8];
    #pragma unroll
    for (int j = 0; j < 8; j++)
        buf[j] = *(const float2*)(ekp + (size_t)j * KLEN);

    float2 acc0 = make_float2(0.f, 0.f), acc1 = make_float2(0.f, 0.f);
    for (int h0 = 0; h0 < HDIM; h0 += 8) {
        float2 nxt[8];
        if (h0 < HDIM - 8) {
            #pragma unroll
            for (int j = 0; j < 8; j++)
                nxt[j] = *(const float2*)(ekp + (size_t)(h0 + 8 + j) * KLEN);
        }
        #pragma unroll
        for (int j = 0; j < 8; j++) {
            float4 e = sm.p.eqw[wav][h0 + j];
            float2 ek = buf[j];
            acc0.x = fmaf(e.z, __builtin_amdgcn_rcpf(fmaf(e.x, ek.x, 1.f)), acc0.x);
            acc0.y = fmaf(e.z, __builtin_amdgcn_rcpf(fmaf(e.x, ek.y, 1.f)), acc0.y);
            acc1.x = fmaf(e.z, __builtin_amdgcn_rcpf(fmaf(e.y, ek.x, 1.f)), acc1.x);
            acc1.y = fmaf(e.z, __builtin_amdgcn_rcpf(fmaf(e.y, ek.y, 1.f)), acc1.y);
        }
        #pragma unroll
        for (int j = 0; j < 8; j++) buf[j] = nxt[j];
    }

    {   // masked exp -> E tile in LDS (el[k][q]); one-time write
        int kg = k0g + kl;
        float e00 = (kg     < vlen) ? __expf(acc0.x) : 0.f;   // q0, k
        float e01 = (kg + 1 < vlen) ? __expf(acc0.y) : 0.f;   // q0, k+1
        float e10 = (kg     < vlen) ? __expf(acc1.x) : 0.f;   // q1, k
        float e11 = (kg + 1 < vlen) ? __expf(acc1.y) : 0.f;   // q1, k+1
        *(float2*)(&sm.p.el[kl][2 * wav])     = make_float2(e00, e10);
        *(float2*)(&sm.p.el[kl + 1][2 * wav]) = make_float2(e01, e11);
    }
    __syncthreads();

    // ---- phase 2: E @ V, wave-exclusive 32-k slice ----
    int kw = wav << 5;                        // wave's k-local base
    int kg0 = k0g + kw;
    int cnt = vlen - kg0; cnt = cnt < 0 ? 0 : (cnt > 32 ? 32 : cnt);
    int cnt4 = (cnt + 3) & ~3;                // el == 0 beyond vlen -> safe
    const float* vb = values + ((size_t)b * KLEN + kg0) * DDIM + (lane << 2);

    float4 acc[8];
    float acct[8];
    #pragma unroll
    for (int q = 0; q < 8; q++) { acc[q] = make_float4(0.f, 0.f, 0.f, 0.f); acct[q] = 0.f; }

    for (int k = 0; k < cnt4; k += 4) {
        #pragma unroll
        for (int j = 0; j < 4; j++) {
            float4 v  = *(const float4*)(vb + (size_t)(k + j) * DDIM);
            float4 p0 = *(const float4*)(&sm.p.el[kw + k + j][0]);
            float4 p1 = *(const float4*)(&sm.p.el[kw + k + j][4]);
            float pq[8] = {p0.x, p0.y, p0.z, p0.w, p1.x, p1.y, p1.z, p1.w};
            #pragma unroll
            for (int q = 0; q < 8; q++) {
                acc[q].x = fmaf(pq[q], v.x, acc[q].x);
                acc[q].y = fmaf(pq[q], v.y, acc[q].y);
                acc[q].z = fmaf(pq[q], v.z, acc[q].z);
                acc[q].w = fmaf(pq[q], v.w, acc[q].w);
                acct[q] += pq[q];
            }
        }
    }

    __syncthreads();               // el reads done; overwrite with slab
    #pragma unroll
    for (int q = 0; q < 8; q++) sm.slab[wav][q][lane] = acc[q];
    if (lane == 0) {
        #pragma unroll
        for (int q = 0; q < 8; q++) tslab[wav][q] = acct[q];
    }
    __syncthreads();
    #pragma unroll
    for (int e = 0; e < 2; e++) {
        int slot = (tid << 1) | e;         // 512 output f4 slots
        int q = slot >> 6, d4 = slot & 63;
        float4 a = sm.slab[0][q][d4];
        #pragma unroll
        for (int g = 1; g < 4; g++) {
            float4 t = sm.slab[g][q][d4];
            a.x += t.x; a.y += t.y; a.z += t.z; a.w += t.w;
        }
        *(float4*)(part + ((size_t)kq * 1024 + bq0 + q) * DDIM + (d4 << 2)) = a;
    }
    if (tid < 8) {
        float t = tslab[0][tid] + tslab[1][tid] + tslab[2][tid] + tslab[3][tid];
        Tp[(size_t)kq * 1024 + bq0 + tid] = t;
    }
}

// ============ sum 8 kq-partials, normalize by T ============
__global__ __launch_bounds__(256) void combine_kernel(
    const float* __restrict__ part, const float* __restrict__ Tp,
    float* __restrict__ out)
{
    int i = blockIdx.x * 256 + threadIdx.x;        // 65536 float4 slots
    int row = i >> 6;                              // 0..1023 (b*64+q)
    const float4* p4 = (const float4*)part;
    float t = 0.f;
    #pragma unroll
    for (int j = 0; j < 8; j++) t += Tp[(size_t)j * 1024 + row];
    float inv = 1.0f / t;
    float4 a = p4[i];
    #pragma unroll
    for (int j = 1; j < 8; j++) {
        float4 v = p4[(size_t)j * 65536 + i];
        a.x += v.x; a.y += v.y; a.z += v.z; a.w += v.w;
    }
    a.x *= inv; a.y *= inv; a.z *= inv; a.w *= inv;
    ((float4*)out)[i] = a;
}

extern "C" void kernel_launch(void* const* d_in, const int* in_sizes, int n_in,
                              void* d_out, int out_size, void* d_ws, size_t ws_size,
                              hipStream_t stream) {
    const float* queries    = (const float*)d_in[0]; // [16,64,256]
    const float* keys       = (const float*)d_in[1]; // [16,1024,256]
    const float* values     = (const float*)d_in[2]; // [16,1024,256]
    const int*   valid_lens = (const int*)d_in[3];   // [16]
    const float* W_q        = (const float*)d_in[4]; // [256,128]
    const float* W_k        = (const float*)d_in[5]; // [256,128]
    const float* w_v        = (const float*)d_in[6]; // [128]

    float* Eq   = (float*)d_ws;            // 1024*128      = 512 KB
    float* Ek   = Eq + 131072;             // 16*128*1024   = 8 MB
    float* part = Ek + 2097152;            // 8*1024*256    = 8 MB (no alias: Ek live)
    float* Tp   = part + 2097152;          // 8*1024 floats = 32 KB

    proj_kernel<<<1088, 256, 0, stream>>>(queries, keys, W_q, W_k, Eq, Ek);
    score_av_kernel<<<1024, 256, 0, stream>>>(Eq, Ek, w_v, valid_lens, values, part, Tp);
    combine_kernel<<<256, 256, 0, stream>>>(part, Tp, (float*)d_out);
}